// Round 15
// baseline (482.157 us; speedup 1.0000x reference)
//
#include <hip/hip_runtime.h>

typedef short s8v __attribute__((ext_vector_type(8)));
typedef float f32x4 __attribute__((ext_vector_type(4)));
typedef unsigned int u32x4 __attribute__((ext_vector_type(4)));

#define LRELU(v) ((v) > 0.f ? (v) : 0.2f * (v))

constexpr int NBK = 391;   // (50000+127)/128 node buckets
constexpr int TILE = 2048; // edges per bin-pass block (391 blocks)
constexpr int CAP = 4096;  // fixed slab capacity per bucket

__device__ __forceinline__ float b2f(unsigned short b) {
  return __uint_as_float(((unsigned int)b) << 16);
}
__device__ __forceinline__ unsigned short f2b(float f) {
  unsigned int x = __float_as_uint(f);
  x += 0x7fffu + ((x >> 16) & 1u);
  return (unsigned short)(x >> 16);
}
__device__ __forceinline__ unsigned int pack2(float lo, float hi) {
  return ((unsigned int)f2b(hi) << 16) | (unsigned int)f2b(lo);
}

// ---------------- fused two-layer MLP: h = lin(lrelu(a1(x)))  ----------------
struct FArgs {
  const unsigned short* X[2];
  const unsigned short* W1[2];
  const float* b1[2];
  const float* a0p[2];
  const float* rowsum[2];
  const unsigned short* W2[2];
  const float* b2[2];
  unsigned short* H[2];
  const float* states;
  int N;
};

__global__ __launch_bounds__(256) void fused_mlp_kernel(FArgs fa)
{
  __shared__ __align__(16) unsigned short Ws[128 * 128];  // W1 then W2 (32KB)
  __shared__ __align__(16) unsigned short Tp[128 * 128];  // swizzled tmp tile (32KB)
  const int d = blockIdx.y;
  const int tid = threadIdx.x;
  const int lane = tid & 63;
  const int w = tid >> 6;
  const int l15 = lane & 15;
  const int g = lane >> 4;
  const int m0 = blockIdx.x * 128;
  const int N = fa.N;

#pragma unroll
  for (int j = 0; j < 8; ++j) {
    int idx = tid + j * 256;
    int o = idx >> 4, c = idx & 15;
    uint4 v = *(const uint4*)(fa.W1[d] + (size_t)o * 128 + c * 8);
    *(uint4*)&Ws[o * 128 + (c ^ (o & 15)) * 8] = v;
  }
  s8v a[2][4];
#pragma unroll
  for (int mf = 0; mf < 2; ++mf) {
    int row = m0 + w * 32 + mf * 16 + l15;
    const unsigned short* ar = fa.X[d] + (size_t)row * 128 + g * 8;
#pragma unroll
    for (int ks = 0; ks < 4; ++ks) {
      s8v t = {};
      if (row < N) t = *(const s8v*)(ar + ks * 32);
      a[mf][ks] = t;
    }
  }
  f32x4 zero4 = {0.f, 0.f, 0.f, 0.f};
  f32x4 acc[2][8];
#pragma unroll
  for (int mf = 0; mf < 2; ++mf)
#pragma unroll
    for (int nf = 0; nf < 8; ++nf) acc[mf][nf] = zero4;
  __syncthreads();
#pragma unroll
  for (int ks = 0; ks < 4; ++ks) {
#pragma unroll
    for (int nf = 0; nf < 8; ++nf) {
      int c = ks * 4 + g;
      s8v b = *(const s8v*)&Ws[(nf * 16 + l15) * 128 + (c ^ l15) * 8];
      acc[0][nf] = __builtin_amdgcn_mfma_f32_16x16x32_bf16(a[0][ks], b, acc[0][nf], 0, 0, 0);
      acc[1][nf] = __builtin_amdgcn_mfma_f32_16x16x32_bf16(a[1][ks], b, acc[1][nf], 0, 0, 0);
    }
  }
  const float a0 = fa.a0p[d][0];
#pragma unroll
  for (int mf = 0; mf < 2; ++mf) {
#pragma unroll
    for (int r = 0; r < 4; ++r) {
      int lrow = w * 32 + mf * 16 + g * 4 + r;
      int row = m0 + lrow;
      float sa = (row < N) ? fa.states[row] * a0 : 0.f;
#pragma unroll
      for (int nf = 0; nf < 8; ++nf) {
        int col = nf * 16 + l15;
        float v = 0.f;
        if (row < N) {
          v = acc[mf][nf][r] + fa.b1[d][col] + sa * fa.rowsum[d][col];
          v = LRELU(v);
        }
        int cch = col >> 3;
        Tp[lrow * 128 + ((cch ^ (lrow & 15)) << 3) + (col & 7)] = f2b(v);
      }
    }
  }
  __syncthreads();
#pragma unroll
  for (int j = 0; j < 8; ++j) {
    int idx = tid + j * 256;
    int o = idx >> 4, c = idx & 15;
    uint4 v = *(const uint4*)(fa.W2[d] + (size_t)o * 128 + c * 8);
    *(uint4*)&Ws[o * 128 + (c ^ (o & 15)) * 8] = v;
  }
  __syncthreads();
#pragma unroll
  for (int mf = 0; mf < 2; ++mf) {
    int lrow = w * 32 + mf * 16 + l15;
#pragma unroll
    for (int ks = 0; ks < 4; ++ks) {
      int c2 = ks * 4 + g;
      a[mf][ks] = *(const s8v*)&Tp[lrow * 128 + ((c2 ^ (lrow & 15)) << 3)];
    }
  }
#pragma unroll
  for (int mf = 0; mf < 2; ++mf)
#pragma unroll
    for (int nf = 0; nf < 8; ++nf) acc[mf][nf] = zero4;
#pragma unroll
  for (int ks = 0; ks < 4; ++ks) {
#pragma unroll
    for (int nf = 0; nf < 8; ++nf) {
      int c = ks * 4 + g;
      s8v b = *(const s8v*)&Ws[(nf * 16 + l15) * 128 + (c ^ l15) * 8];
      acc[0][nf] = __builtin_amdgcn_mfma_f32_16x16x32_bf16(a[0][ks], b, acc[0][nf], 0, 0, 0);
      acc[1][nf] = __builtin_amdgcn_mfma_f32_16x16x32_bf16(a[1][ks], b, acc[1][nf], 0, 0, 0);
    }
  }
#pragma unroll
  for (int mf = 0; mf < 2; ++mf) {
#pragma unroll
    for (int r = 0; r < 4; ++r) {
      int row = m0 + w * 32 + mf * 16 + g * 4 + r;
      if (row >= N) continue;
      unsigned short* crow = fa.H[d] + (size_t)row * 128;
#pragma unroll
      for (int nf = 0; nf < 8; ++nf) {
        int col = nf * 16 + l15;
        crow[col] = f2b(acc[mf][nf][r] + fa.b2[d][col]);
      }
    }
  }
}

// ---------------- fused beta (64KB LDS) ----------------
struct PBArgs {
  const unsigned short* U[2];
  const unsigned short* Wb[2];
  const unsigned short* Wb2;
  const float* bias;
  unsigned short* XC;
  int N;
};

__global__ __launch_bounds__(256) void fused_beta_kernel(PBArgs pa)
{
  __shared__ __align__(16) unsigned short Ws[128 * 128];
  __shared__ __align__(16) unsigned short Tp[128 * 128];
  const int tid = threadIdx.x;
  const int lane = tid & 63;
  const int w = tid >> 6;
  const int l15 = lane & 15;
  const int g = lane >> 4;
  const int m0 = blockIdx.x * 128;
  const int N = pa.N;
  f32x4 zero4 = {0.f, 0.f, 0.f, 0.f};
  s8v a[2][4];
  f32x4 accf[2][8];
#pragma unroll
  for (int mf = 0; mf < 2; ++mf)
#pragma unroll
    for (int nf = 0; nf < 8; ++nf) accf[mf][nf] = zero4;

  for (int ph = 0; ph < 2; ++ph) {
#pragma unroll
    for (int j = 0; j < 8; ++j) {
      int idx = tid + j * 256;
      int o = idx >> 4, c = idx & 15;
      uint4 v = *(const uint4*)(pa.Wb[ph] + (size_t)o * 128 + c * 8);
      *(uint4*)&Ws[o * 128 + (c ^ (o & 15)) * 8] = v;
    }
#pragma unroll
    for (int mf = 0; mf < 2; ++mf) {
      int row = m0 + w * 32 + mf * 16 + l15;
      const unsigned short* ar = pa.U[ph] + (size_t)row * 128 + g * 8;
#pragma unroll
      for (int ks = 0; ks < 4; ++ks) {
        s8v t = {};
        if (row < N) t = *(const s8v*)(ar + ks * 32);
        a[mf][ks] = t;
      }
    }
    f32x4 acc[2][8];
#pragma unroll
    for (int mf = 0; mf < 2; ++mf)
#pragma unroll
      for (int nf = 0; nf < 8; ++nf) acc[mf][nf] = zero4;
    __syncthreads();
#pragma unroll
    for (int ks = 0; ks < 4; ++ks) {
#pragma unroll
      for (int nf = 0; nf < 8; ++nf) {
        int c = ks * 4 + g;
        s8v b = *(const s8v*)&Ws[(nf * 16 + l15) * 128 + (c ^ l15) * 8];
        acc[0][nf] = __builtin_amdgcn_mfma_f32_16x16x32_bf16(a[0][ks], b, acc[0][nf], 0, 0, 0);
        acc[1][nf] = __builtin_amdgcn_mfma_f32_16x16x32_bf16(a[1][ks], b, acc[1][nf], 0, 0, 0);
      }
    }
    __syncthreads();
#pragma unroll
    for (int mf = 0; mf < 2; ++mf) {
#pragma unroll
      for (int r = 0; r < 4; ++r) {
        int lrow = w * 32 + mf * 16 + g * 4 + r;
        int row = m0 + lrow;
#pragma unroll
        for (int nf = 0; nf < 8; ++nf) {
          int col = nf * 16 + l15;
          float v = (row < N) ? acc[mf][nf][r] : 0.f;
          int cch = col >> 3;
          Tp[lrow * 128 + ((cch ^ (lrow & 15)) << 3) + (col & 7)] = f2b(v);
        }
      }
    }
    __syncthreads();
#pragma unroll
    for (int j = 0; j < 8; ++j) {
      int idx = tid + j * 256;
      int o = idx >> 4, c = idx & 15;
      uint4 v = *(const uint4*)(pa.Wb2 + (size_t)o * 256 + ph * 128 + c * 8);
      *(uint4*)&Ws[o * 128 + (c ^ (o & 15)) * 8] = v;
    }
#pragma unroll
    for (int mf = 0; mf < 2; ++mf) {
      int lrow = w * 32 + mf * 16 + l15;
#pragma unroll
      for (int ks = 0; ks < 4; ++ks) {
        int c2 = ks * 4 + g;
        a[mf][ks] = *(const s8v*)&Tp[lrow * 128 + ((c2 ^ (lrow & 15)) << 3)];
      }
    }
    __syncthreads();
#pragma unroll
    for (int ks = 0; ks < 4; ++ks) {
#pragma unroll
      for (int nf = 0; nf < 8; ++nf) {
        int c = ks * 4 + g;
        s8v b = *(const s8v*)&Ws[(nf * 16 + l15) * 128 + (c ^ l15) * 8];
        accf[0][nf] = __builtin_amdgcn_mfma_f32_16x16x32_bf16(a[0][ks], b, accf[0][nf], 0, 0, 0);
        accf[1][nf] = __builtin_amdgcn_mfma_f32_16x16x32_bf16(a[1][ks], b, accf[1][nf], 0, 0, 0);
      }
    }
    __syncthreads();
  }
#pragma unroll
  for (int mf = 0; mf < 2; ++mf) {
#pragma unroll
    for (int r = 0; r < 4; ++r) {
      int row = m0 + w * 32 + mf * 16 + g * 4 + r;
      if (row >= N) continue;
      unsigned short* crow = pa.XC + (size_t)row * 128;
#pragma unroll
      for (int nf = 0; nf < 8; ++nf) {
        int col = nf * 16 + l15;
        float v = accf[mf][nf][r] + pa.bias[col];
        crow[col] = f2b(LRELU(v));
      }
    }
  }
}

// ---------------- g3 GEMM with fused g0 stage + final dot ----------------
__global__ __launch_bounds__(256) void g3_kernel(
    const unsigned short* __restrict__ xc,
    const unsigned short* __restrict__ A16,
    const unsigned short* __restrict__ B16,
    const int* __restrict__ batch,
    const unsigned short* __restrict__ W0,
    const unsigned short* __restrict__ W3,
    const float* __restrict__ g4W,
    const float* __restrict__ g4b,
    float* __restrict__ out, int N)
{
  constexpr int NF = 12;
  __shared__ __align__(16) unsigned short Ws[192 * 128];
  __shared__ __align__(16) unsigned short Tp[128 * 128];
  const int tid = threadIdx.x;
  const int lane = tid & 63;
  const int w = tid >> 6;
  const int l15 = lane & 15;
  const int g = lane >> 4;
  const int m0 = blockIdx.x * 128;

  f32x4 zero4 = {0.f, 0.f, 0.f, 0.f};
  s8v a[2][4];

#pragma unroll
  for (int j = 0; j < 8; ++j) {
    int idx = tid + j * 256;
    int o = idx >> 4, c = idx & 15;
    uint4 v = *(const uint4*)(W0 + (size_t)o * 128 + c * 8);
    *(uint4*)&Ws[o * 128 + (c ^ (o & 15)) * 8] = v;
  }
#pragma unroll
  for (int mf = 0; mf < 2; ++mf) {
    int row = m0 + w * 32 + mf * 16 + l15;
    const unsigned short* ar = xc + (size_t)row * 128 + g * 8;
#pragma unroll
    for (int ks = 0; ks < 4; ++ks) {
      s8v t = {};
      if (row < N) t = *(const s8v*)(ar + ks * 32);
      a[mf][ks] = t;
    }
  }
  {
    f32x4 acc1[2][8];
#pragma unroll
    for (int mf = 0; mf < 2; ++mf)
#pragma unroll
      for (int nf = 0; nf < 8; ++nf) acc1[mf][nf] = zero4;
    __syncthreads();
#pragma unroll
    for (int ks = 0; ks < 4; ++ks) {
#pragma unroll
      for (int nf = 0; nf < 8; ++nf) {
        int c = ks * 4 + g;
        s8v b = *(const s8v*)&Ws[(nf * 16 + l15) * 128 + (c ^ l15) * 8];
        acc1[0][nf] = __builtin_amdgcn_mfma_f32_16x16x32_bf16(a[0][ks], b, acc1[0][nf], 0, 0, 0);
        acc1[1][nf] = __builtin_amdgcn_mfma_f32_16x16x32_bf16(a[1][ks], b, acc1[1][nf], 0, 0, 0);
      }
    }
#pragma unroll
    for (int mf = 0; mf < 2; ++mf) {
#pragma unroll
      for (int r = 0; r < 4; ++r) {
        int lrow = w * 32 + mf * 16 + g * 4 + r;
        int row = m0 + lrow;
#pragma unroll
        for (int nf = 0; nf < 8; ++nf) {
          int col = nf * 16 + l15;
          float v = (row < N) ? acc1[mf][nf][r] : 0.f;
          int cch = col >> 3;
          Tp[lrow * 128 + ((cch ^ (lrow & 15)) << 3) + (col & 7)] = f2b(v);
        }
      }
    }
  }
  __syncthreads();

  f32x4 acc[2][NF];
#pragma unroll
  for (int mf = 0; mf < 2; ++mf)
#pragma unroll
    for (int nf = 0; nf < NF; ++nf) acc[mf][nf] = zero4;

  int brow[2];
#pragma unroll
  for (int mf = 0; mf < 2; ++mf) {
    int row = m0 + w * 32 + mf * 16 + l15;
    brow[mf] = (row < N) ? batch[row] : 0;
  }

  for (int kk = 0; kk < 384; kk += 128) {
#pragma unroll
    for (int j = 0; j < NF; ++j) {
      int idx = tid + j * 256;
      int o = idx >> 4, c = idx & 15;
      uint4 v = *(const uint4*)(W3 + (size_t)o * 384 + kk + c * 8);
      *(uint4*)&Ws[o * 128 + (c ^ (o & 15)) * 8] = v;
    }
    if (kk == 0) {
#pragma unroll
      for (int mf = 0; mf < 2; ++mf) {
        int lrow = w * 32 + mf * 16 + l15;
#pragma unroll
        for (int ks = 0; ks < 4; ++ks) {
          int c2 = ks * 4 + g;
          a[mf][ks] = *(const s8v*)&Tp[lrow * 128 + ((c2 ^ (lrow & 15)) << 3)];
        }
      }
    } else {
#pragma unroll
      for (int mf = 0; mf < 2; ++mf) {
        int row = m0 + w * 32 + mf * 16 + l15;
        const unsigned short* ar = ((kk == 128) ? A16 : B16) + (size_t)brow[mf] * 128 + g * 8;
#pragma unroll
        for (int ks = 0; ks < 4; ++ks) {
          s8v t = {};
          if (row < N) t = *(const s8v*)(ar + ks * 32);
          a[mf][ks] = t;
        }
      }
    }
    __syncthreads();
#pragma unroll
    for (int ks = 0; ks < 4; ++ks) {
#pragma unroll
      for (int nf = 0; nf < NF; ++nf) {
        int c = ks * 4 + g;
        s8v b = *(const s8v*)&Ws[(nf * 16 + l15) * 128 + (c ^ l15) * 8];
        acc[0][nf] = __builtin_amdgcn_mfma_f32_16x16x32_bf16(a[0][ks], b, acc[0][nf], 0, 0, 0);
        acc[1][nf] = __builtin_amdgcn_mfma_f32_16x16x32_bf16(a[1][ks], b, acc[1][nf], 0, 0, 0);
      }
    }
    if (kk < 256) __syncthreads();
  }

  float w4[NF];
#pragma unroll
  for (int nf = 0; nf < NF; ++nf) w4[nf] = g4W[nf * 16 + l15];
  const float gb = g4b[0];

#pragma unroll
  for (int mf = 0; mf < 2; ++mf) {
#pragma unroll
    for (int r = 0; r < 4; ++r) {
      int row = m0 + w * 32 + mf * 16 + g * 4 + r;
      float dot = 0.f;
#pragma unroll
      for (int nf = 0; nf < NF; ++nf) {
        float v = acc[mf][nf][r];
        v = LRELU(v);
        dot += v * w4[nf];
      }
#pragma unroll
      for (int m = 1; m < 16; m <<= 1) dot += __shfl_xor(dot, m, 16);
      if (l15 == 0 && row < N) out[row] = dot + gb;
    }
  }
}

// ---------------- preamble: convert weights + rowsums + init x split + zero bcur ----------------
struct PreArgs {
  const float* src[9];
  unsigned short* wreg;
  int cum[10];
  const float* a1; const float* a2; float* rs;
  const float* x;
  unsigned short* x1; unsigned short* x2;
  int* bcur0; int* bcur1;
  int n;
};

__global__ __launch_bounds__(256) void preamble_kernel(PreArgs pa)
{
  const int NINIT = 3125;
  const int NCONV = 172;
  int b = blockIdx.x;
  int t = threadIdx.x;
  if (b < NINIT) {
    int idx = b * 256 + t;
    if (idx < pa.n * 16) {
      int r = idx >> 4, c = idx & 15;
      const float* xr = pa.x + (size_t)r * 256 + c * 8;
      float4 p0 = *(const float4*)xr;
      float4 p1 = *(const float4*)(xr + 4);
      uint4 u1;
      u1.x = pack2(p0.x, p0.y); u1.y = pack2(p0.z, p0.w);
      u1.z = pack2(p1.x, p1.y); u1.w = pack2(p1.z, p1.w);
      float4 q0 = *(const float4*)(xr + 128);
      float4 q1 = *(const float4*)(xr + 132);
      uint4 u2;
      u2.x = pack2(q0.x, q0.y); u2.y = pack2(q0.z, q0.w);
      u2.z = pack2(q1.x, q1.y); u2.w = pack2(q1.z, q1.w);
      ((uint4*)(pa.x1 + (size_t)r * 128))[c] = u1;
      ((uint4*)(pa.x2 + (size_t)r * 128))[c] = u2;
    }
  } else if (b < NINIT + NCONV) {
    int e = ((b - NINIT) * 256 + t) * 8;
    if (e < pa.cum[9]) {
      int j = 0;
#pragma unroll
      for (int k = 1; k < 9; ++k) if (e >= pa.cum[k]) j = k;
      const float* s = pa.src[j] + (e - pa.cum[j]);
      float4 p0 = *(const float4*)s;
      float4 p1 = *(const float4*)(s + 4);
      uint4 u;
      u.x = pack2(p0.x, p0.y); u.y = pack2(p0.z, p0.w);
      u.z = pack2(p1.x, p1.y); u.w = pack2(p1.z, p1.w);
      *(uint4*)(pa.wreg + e) = u;
    }
  } else if (b < NINIT + NCONV + 6) {
    int j = b - NINIT - NCONV;
    if (t < 128) {
      const float* src = (j < 3) ? (pa.a1 + (size_t)j * 16384) : (pa.a2 + (size_t)(j - 3) * 16384);
      float s = 0.f;
      for (int k = 0; k < 128; ++k) s += src[t * 128 + k];
      pa.rs[j * 128 + t] = s;
    }
  } else {
    for (int i = t; i < NBK; i += 256) { pa.bcur0[i] = 0; pa.bcur1[i] = 0; }
  }
}

// ---------------- multi-split bin pass into fixed-cap per-bucket slabs ----------------
struct BinArgs {
  const int* s0; const int* s1; const float* ew;
  int* bcur0; int* bcur1;
  unsigned long long* bin0; unsigned long long* bin1;
  int E;
};
__global__ __launch_bounds__(256) void bin_kernel(BinArgs ba)
{
  __shared__ int hist0[NBK], hist1[NBK];
  __shared__ int base0[NBK], base1[NBK];
  const int t = threadIdx.x;
  const int e0 = blockIdx.x * TILE;
  const int e1 = min(e0 + TILE, ba.E);
  for (int i = t; i < NBK; i += 256) { hist0[i] = 0; hist1[i] = 0; }
  __syncthreads();
  for (int e = e0 + t; e < e1; e += 256) {
    atomicAdd(&hist0[ba.s0[e] >> 7], 1);
    atomicAdd(&hist1[ba.s1[e] >> 7], 1);
  }
  __syncthreads();
  for (int i = t; i < NBK; i += 256) {
    int c0 = hist0[i];
    base0[i] = c0 ? atomicAdd(&ba.bcur0[i], c0) : 0;
    int c1 = hist1[i];
    base1[i] = c1 ? atomicAdd(&ba.bcur1[i], c1) : 0;
  }
  __syncthreads();
  for (int i = t; i < NBK; i += 256) { hist0[i] = 0; hist1[i] = 0; }
  __syncthreads();
  for (int e = e0 + t; e < e1; e += 256) {
    int d0 = ba.s0[e], d1 = ba.s1[e];
    unsigned long long wb = (unsigned long long)__float_as_uint(ba.ew[e]) << 32;
    int b0 = d0 >> 7, b1 = d1 >> 7;
    int r0 = base0[b0] + atomicAdd(&hist0[b0], 1);
    if (r0 < CAP)
      ba.bin0[(size_t)b0 * CAP + r0] = wb | (unsigned int)((d0 & 127) << 16) | (unsigned int)d1;
    int r1 = base1[b1] + atomicAdd(&hist1[b1], 1);
    if (r1 < CAP)
      ba.bin1[(size_t)b1 * CAP + r1] = wb | (unsigned int)((d1 & 127) << 16) | (unsigned int)d0;
  }
}

// ---------------- bucket scan + gsel/gsum zero ----------------
struct BScanArgs { const int* cnt[2]; int* bbase[2]; float* gsel; float* gsum; };
__global__ __launch_bounds__(128) void bscan_kernel(BScanArgs a)
{
  __shared__ int ld[2][NBK];
  int wid = threadIdx.x >> 6, lane = threadIdx.x & 63;
  for (int i = threadIdx.x; i < 2048; i += 128) { a.gsel[i] = 0.f; a.gsum[i] = 0.f; }
  for (int i = lane; i < NBK; i += 64) ld[wid][i] = a.cnt[wid][i];
  __syncthreads();
  if (lane == 0) {
    int acc = 0;
    for (int i = 0; i < NBK; ++i) { int v = ld[wid][i]; ld[wid][i] = acc; acc += v; }
    a.bbase[wid][NBK] = acc;
  }
  __syncthreads();
  for (int i = lane; i < NBK; i += 64) a.bbase[wid][i] = ld[wid][i];
}

// ---------------- reorder: slab -> per-node CSR slots + row[] build ----------------
struct RArgs {
  const int* bbase[2];
  const unsigned long long* bin[2];
  unsigned int* comb[2];
  int* row[2];
  int n;
};
__global__ __launch_bounds__(256) void reorder_kernel(RArgs ra)
{
  const int d = blockIdx.y;
  const int b = blockIdx.x;
  const unsigned long long* __restrict__ bin = ra.bin[d] + (size_t)b * CAP;
  unsigned int* __restrict__ comb = ra.comb[d];
  int* __restrict__ row = ra.row[d];
  const int nb = b * 128;
  const int ne = min(nb + 128, ra.n);
  const int t = threadIdx.x;
  __shared__ int lcnt[128];
  __shared__ int lcur[128];
  __shared__ int wtot[4];
  if (t < 128) lcnt[t] = 0;
  const int span_beg = ra.bbase[d][b];
  const int span_end = ra.bbase[d][b + 1];
  const int cnt = span_end - span_beg;
  __syncthreads();
  for (int i = t; i < cnt; i += 256) {
    int nl = ((unsigned int)bin[i] >> 16) & 127;
    atomicAdd(&lcnt[nl], 1);
  }
  __syncthreads();
  int lane = t & 63, wv = t >> 6;
  int v = (t < 128) ? lcnt[t] : 0;
  int sc = v;
#pragma unroll
  for (int off = 1; off < 64; off <<= 1) {
    int u = __shfl_up(sc, off, 64);
    if (lane >= off) sc += u;
  }
  if (lane == 63) wtot[wv] = sc;
  __syncthreads();
  int excl = sc - v + ((wv == 1) ? wtot[0] : 0);
  if (t < 128) {
    lcur[t] = excl;
    if (nb + t < ne) row[nb + t] = span_beg + excl;
  }
  if (b == NBK - 1 && t == 0) row[ra.n] = span_end;
  __syncthreads();
  for (int i = t; i < cnt; i += 256) {
    unsigned long long r = bin[i];
    unsigned int lo = (unsigned int)r;
    float w = __uint_as_float((unsigned int)(r >> 32));
    int nl = (lo >> 16) & 127;
    int slot = atomicAdd(&lcur[nl], 1);
    comb[span_beg + slot] = (lo & 0xffffu) | ((unsigned int)f2b(w) << 16);
  }
}

// gather v5: node per quarter-wave; uint4 h loads; aligned chunks, uint4 NT comb loads
struct GArgs {
  const int* rowstart[2];
  const unsigned int* comb[2];
  const unsigned short* h[2];
  unsigned short* xout[2];
  const unsigned int* add1[2];
  const unsigned int* add2[2];
  int n;
};
__global__ void gather_kernel(GArgs ga)
{
  int quad = blockIdx.x * (blockDim.x >> 6) + (threadIdx.x >> 6);
  int lane = threadIdx.x & 63;
  int sub = lane >> 4;        // node slot 0..3
  int fl = lane & 15;         // feature lane: uint4 = 8 bf16 features
  long long gnode = (long long)4 * quad + sub;
  bool valid = gnode < 2 * ga.n;
  int dir = (valid && gnode >= ga.n) ? 1 : 0;
  int node = valid ? (int)(gnode - (long long)dir * ga.n) : 0;
  const int* __restrict__ rowstart = ga.rowstart[dir];
  const unsigned int* __restrict__ comb = ga.comb[dir];
  const unsigned int* __restrict__ h = (const unsigned int*)ga.h[dir];
  int beg = rowstart[node], end = rowstart[node + 1];
  if (!valid) { beg = 0; end = 0; }
  int pstart = beg & ~7;      // align chunks to 8-record boundaries
  int nch_own = (end - pstart + 7) >> 3;
  if (end <= pstart) nch_own = 0;
  int m1 = max(nch_own, __shfl_xor(nch_own, 16, 64));
  int nch = max(m1, __shfl_xor(m1, 32, 64));
  float a0 = 0.f, a1 = 0.f, a2 = 0.f, a3 = 0.f;
  float a4 = 0.f, a5 = 0.f, a6 = 0.f, a7 = 0.f;
  for (int ch = 0; ch < nch; ++ch) {
    int p0 = pstart + ch * 8;
    u32x4 ca = __builtin_nontemporal_load((const u32x4*)(comb + p0));
    u32x4 cb = __builtin_nontemporal_load((const u32x4*)(comb + p0 + 4));
    unsigned int cc[8];
    cc[0] = ca.x; cc[1] = ca.y; cc[2] = ca.z; cc[3] = ca.w;
    cc[4] = cb.x; cc[5] = cb.y; cc[6] = cb.z; cc[7] = cb.w;
    uint4 uu[8];
#pragma unroll
    for (int i = 0; i < 8; ++i)
      uu[i] = *(const uint4*)(h + (size_t)(cc[i] & 0xffffu) * 64 + fl * 4);
#pragma unroll
    for (int i = 0; i < 8; ++i) {
      int pi = p0 + i;
      float wv = (pi >= beg && pi < end) ? b2f((unsigned short)(cc[i] >> 16)) : 0.f;
      a0 += wv * b2f((unsigned short)uu[i].x);
      a1 += wv * b2f((unsigned short)(uu[i].x >> 16));
      a2 += wv * b2f((unsigned short)uu[i].y);
      a3 += wv * b2f((unsigned short)(uu[i].y >> 16));
      a4 += wv * b2f((unsigned short)uu[i].z);
      a5 += wv * b2f((unsigned short)(uu[i].z >> 16));
      a6 += wv * b2f((unsigned short)uu[i].w);
      a7 += wv * b2f((unsigned short)(uu[i].w >> 16));
    }
  }
  float v0 = LRELU(a0), v1 = LRELU(a1), v2 = LRELU(a2), v3 = LRELU(a3);
  float v4 = LRELU(a4), v5 = LRELU(a5), v6 = LRELU(a6), v7 = LRELU(a7);
  if (ga.add1[0]) {
    u32x4 ua = __builtin_nontemporal_load((const u32x4*)ga.add1[dir] + (size_t)node * 16 + fl);
    u32x4 ub = __builtin_nontemporal_load((const u32x4*)ga.add2[dir] + (size_t)node * 16 + fl);
    v0 += b2f((unsigned short)ua.x) + b2f((unsigned short)ub.x);
    v1 += b2f((unsigned short)(ua.x >> 16)) + b2f((unsigned short)(ub.x >> 16));
    v2 += b2f((unsigned short)ua.y) + b2f((unsigned short)ub.y);
    v3 += b2f((unsigned short)(ua.y >> 16)) + b2f((unsigned short)(ub.y >> 16));
    v4 += b2f((unsigned short)ua.z) + b2f((unsigned short)ub.z);
    v5 += b2f((unsigned short)(ua.z >> 16)) + b2f((unsigned short)(ub.z >> 16));
    v6 += b2f((unsigned short)ua.w) + b2f((unsigned short)ub.w);
    v7 += b2f((unsigned short)(ua.w >> 16)) + b2f((unsigned short)(ub.w >> 16));
  }
  if (valid) {
    u32x4 o;
    o.x = pack2(v0, v1);
    o.y = pack2(v2, v3);
    o.z = pack2(v4, v5);
    o.w = pack2(v6, v7);
    __builtin_nontemporal_store(o, (u32x4*)(ga.xout[dir] + (size_t)node * 128) + fl);
  }
}

// ---------------- parallel segment sum ----------------
__global__ __launch_bounds__(256) void segsum_kernel(
    const unsigned short* __restrict__ xc, const int* __restrict__ batch,
    const float* __restrict__ states,
    float* __restrict__ gsel, float* __restrict__ gsum, int n)
{
  int slot = threadIdx.x >> 6;
  int lane = threadIdx.x & 63;
  int r0 = blockIdx.x * 128 + slot * 32;
  if (r0 >= n) return;
  int r1 = min(r0 + 32, n);
  const unsigned int* __restrict__ xcu = (const unsigned int*)xc;
  float sel0 = 0.f, sel1 = 0.f, sum0 = 0.f, sum1 = 0.f;
  int cur = batch[r0];
  for (int r = r0; r < r1; r += 4) {
    unsigned int u[4]; int bb[4]; float st[4];
#pragma unroll
    for (int i = 0; i < 4; ++i) {
      int ri = min(r + i, r1 - 1);
      u[i] = xcu[(size_t)ri * 64 + lane];
      bb[i] = batch[ri];
      st[i] = states[ri];
    }
    int m = min(4, r1 - r);
#pragma unroll
    for (int i = 0; i < 4; ++i) {
      if (i >= m) break;
      if (bb[i] != cur) {
        atomicAdd(&gsel[cur * 128 + lane * 2], sel0);
        atomicAdd(&gsel[cur * 128 + lane * 2 + 1], sel1);
        atomicAdd(&gsum[cur * 128 + lane * 2], sum0);
        atomicAdd(&gsum[cur * 128 + lane * 2 + 1], sum1);
        sel0 = sel1 = sum0 = sum1 = 0.f;
        cur = bb[i];
      }
      float lo = b2f((unsigned short)u[i]);
      float hi = b2f((unsigned short)(u[i] >> 16));
      sum0 += lo; sum1 += hi;
      if (st[i] == 1.0f) { sel0 += lo; sel1 += hi; }
    }
  }
  atomicAdd(&gsel[cur * 128 + lane * 2], sel0);
  atomicAdd(&gsel[cur * 128 + lane * 2 + 1], sel1);
  atomicAdd(&gsum[cur * 128 + lane * 2], sum0);
  atomicAdd(&gsum[cur * 128 + lane * 2 + 1], sum1);
}

__global__ void small16_kernel(const float* __restrict__ gsel, const float* __restrict__ gsum,
                               const float* __restrict__ g1W, const float* __restrict__ g2W,
                               unsigned short* __restrict__ A16, unsigned short* __restrict__ B16)
{
  int r = blockIdx.x, t = threadIdx.x, o = t & 127;
  const float* src = (t < 128) ? gsel : gsum;
  const float* Wm  = (t < 128) ? g1W : g2W;
  float acc = 0.f;
  for (int k = 0; k < 128; ++k) acc += src[r * 128 + k] * Wm[o * 128 + k];
  unsigned short* dst = (t < 128) ? A16 : B16;
  dst[r * 128 + o] = f2b(acc);
}

extern "C" void kernel_launch(void* const* d_in, const int* in_sizes, int n_in,
                              void* d_out, int out_size, void* d_ws, size_t ws_size,
                              hipStream_t stream)
{
  const int N = 50000, F = 128, E = 800000, G = 16, T = 3;
  const float* x      = (const float*)d_in[0];
  const int*   ei     = (const int*)d_in[1];
  const int*   s0     = ei;
  const int*   s1     = ei + E;
  const float* ew     = (const float*)d_in[2];
  const int*   batch  = (const int*)d_in[3];
  const float* states = (const float*)d_in[4];
  const float* p_a0[2]   = {(const float*)d_in[5],  (const float*)d_in[10]};
  const float* p_a1W[2]  = {(const float*)d_in[6],  (const float*)d_in[11]};
  const float* p_a1b[2]  = {(const float*)d_in[7],  (const float*)d_in[12]};
  const float* p_linW[2] = {(const float*)d_in[8],  (const float*)d_in[13]};
  const float* p_linb[2] = {(const float*)d_in[9],  (const float*)d_in[14]};
  const float* beta0W = (const float*)d_in[15];
  const float* beta1W = (const float*)d_in[16];
  const float* beta2W = (const float*)d_in[17];
  const float* beta2b = (const float*)d_in[18];
  const float* g0W = (const float*)d_in[19];
  const float* g1W = (const float*)d_in[20];
  const float* g2W = (const float*)d_in[21];
  const float* g3W = (const float*)d_in[22];
  const float* g4W = (const float*)d_in[23];
  const float* g4b = (const float*)d_in[24];
  float* out = (float*)d_out;

  char* p = (char*)d_ws;
  auto alloc = [&](size_t bytes) {
    char* r = p;
    p += (bytes + 255) & ~(size_t)255;
    return r;
  };
  const size_t NFb2 = (size_t)N * F * sizeof(unsigned short);  // 12.8 MB
  unsigned short* X1[3] = {(unsigned short*)alloc(NFb2), (unsigned short*)alloc(NFb2),
                           (unsigned short*)alloc(NFb2)};
  unsigned short* X2[3] = {(unsigned short*)alloc(NFb2), (unsigned short*)alloc(NFb2),
                           (unsigned short*)alloc(NFb2)};
  unsigned short* TMP0 = (unsigned short*)alloc(NFb2);
  unsigned short* TMP1 = (unsigned short*)alloc(NFb2);
  unsigned short* HH0  = (unsigned short*)alloc(NFb2);
  unsigned short* HH1  = (unsigned short*)alloc(NFb2);
  int*   row0 = (int*)alloc((size_t)(N + 1) * 4);
  int*   row1 = (int*)alloc((size_t)(N + 1) * 4);
  int*   bbase0 = (int*)alloc((size_t)(NBK + 1) * 4);
  int*   bbase1 = (int*)alloc((size_t)(NBK + 1) * 4);
  int*   bcur0 = (int*)alloc((size_t)NBK * 4);
  int*   bcur1 = (int*)alloc((size_t)NBK * 4);
  unsigned long long* bin0 = (unsigned long long*)alloc((size_t)NBK * CAP * 8);
  unsigned long long* bin1 = (unsigned long long*)alloc((size_t)NBK * CAP * 8);
  unsigned int* comb0 = (unsigned int*)alloc((size_t)E * 4);
  unsigned int* comb1 = (unsigned int*)alloc((size_t)E * 4);
  float* gsel = (float*)alloc((size_t)G * F * 4);
  float* gsum = (float*)alloc((size_t)G * F * 4);
  unsigned short* A16b = (unsigned short*)alloc((size_t)G * F * 2);
  unsigned short* B16b = (unsigned short*)alloc((size_t)G * F * 2);
  unsigned short* wreg = (unsigned short*)alloc((size_t)352256 * 2);
  float* rs = (float*)alloc((size_t)6 * 128 * 4);

  unsigned short* a1Wb[2]  = {wreg + 0,      wreg + 49152};
  unsigned short* linWb[2] = {wreg + 98304,  wreg + 147456};
  unsigned short* b0b = wreg + 196608;
  unsigned short* b1b = wreg + 212992;
  unsigned short* b2b = wreg + 229376;
  unsigned short* g0b = wreg + 262144;
  unsigned short* g3b = wreg + 278528;

  const dim3 blk256(256);
  const int GX = (N + 127) / 128;
  const int EB = (E + TILE - 1) / TILE;

  // ---- preamble: convert + rowsum + init + zero-bcur in ONE launch ----
  PreArgs pra;
  pra.src[0] = p_a1W[0];  pra.src[1] = p_a1W[1];
  pra.src[2] = p_linW[0]; pra.src[3] = p_linW[1];
  pra.src[4] = beta0W;    pra.src[5] = beta1W;  pra.src[6] = beta2W;
  pra.src[7] = g0W;       pra.src[8] = g3W;
  pra.wreg = wreg;
  int cums[10] = {0, 49152, 98304, 147456, 196608, 212992, 229376, 262144, 278528, 352256};
  for (int i = 0; i < 10; ++i) pra.cum[i] = cums[i];
  pra.a1 = p_a1W[0]; pra.a2 = p_a1W[1]; pra.rs = rs;
  pra.x = x; pra.x1 = X1[0]; pra.x2 = X2[0];
  pra.bcur0 = bcur0; pra.bcur1 = bcur1;
  pra.n = N;
  preamble_kernel<<<3125 + 172 + 6 + 1, blk256, 0, stream>>>(pra);

  // ---- CSR build ----
  BinArgs bna;
  bna.s0 = s0; bna.s1 = s1; bna.ew = ew;
  bna.bcur0 = bcur0; bna.bcur1 = bcur1;
  bna.bin0 = bin0; bna.bin1 = bin1;
  bna.E = E;
  bin_kernel<<<EB, blk256, 0, stream>>>(bna);
  BScanArgs bsa;
  bsa.cnt[0] = bcur0; bsa.cnt[1] = bcur1;
  bsa.bbase[0] = bbase0; bsa.bbase[1] = bbase1;
  bsa.gsel = gsel; bsa.gsum = gsum;
  bscan_kernel<<<1, 128, 0, stream>>>(bsa);
  RArgs ra;
  ra.bbase[0] = bbase0; ra.bbase[1] = bbase1;
  ra.bin[0] = bin0; ra.bin[1] = bin1;
  ra.comb[0] = comb0; ra.comb[1] = comb1;
  ra.row[0] = row0; ra.row[1] = row1;
  ra.n = N;
  reorder_kernel<<<dim3(NBK, 2), blk256, 0, stream>>>(ra);

  // ---- T-loop ----
  for (int t = 0; t < T; ++t) {
    int rv = t % 3, wv = (t + 1) % 3;

    FArgs fa;
    fa.X[0] = X1[rv];  fa.X[1] = X2[rv];
    fa.W1[0] = a1Wb[0] + t * 16384;  fa.W1[1] = a1Wb[1] + t * 16384;
    fa.b1[0] = p_a1b[0] + t * F;     fa.b1[1] = p_a1b[1] + t * F;
    fa.a0p[0] = p_a0[0] + t;         fa.a0p[1] = p_a0[1] + t;
    fa.rowsum[0] = rs + t * 128;     fa.rowsum[1] = rs + (3 + t) * 128;
    fa.W2[0] = linWb[0] + t * 16384; fa.W2[1] = linWb[1] + t * 16384;
    fa.b2[0] = p_linb[0] + t * F;    fa.b2[1] = p_linb[1] + t * F;
    fa.H[0] = HH0;  fa.H[1] = HH1;
    fa.states = states;  fa.N = N;
    fused_mlp_kernel<<<dim3(GX, 2), blk256, 0, stream>>>(fa);

    GArgs ga;
    ga.rowstart[0] = row0; ga.rowstart[1] = row1;
    ga.comb[0] = comb0;    ga.comb[1] = comb1;
    ga.h[0] = HH0;         ga.h[1] = HH1;
    if (t == T - 1) {
      ga.xout[0] = TMP0;  ga.xout[1] = TMP1;
      ga.add1[0] = (const unsigned int*)X1[1];  ga.add1[1] = (const unsigned int*)X2[1];
      ga.add2[0] = (const unsigned int*)X1[2];  ga.add2[1] = (const unsigned int*)X2[2];
    } else {
      ga.xout[0] = X1[wv];  ga.xout[1] = X2[wv];
      ga.add1[0] = nullptr; ga.add1[1] = nullptr;
      ga.add2[0] = nullptr; ga.add2[1] = nullptr;
    }
    ga.n = N;
    gather_kernel<<<(2 * N + 15) / 16, blk256, 0, stream>>>(ga);
  }

  // ---- fused beta ----
  PBArgs pb;
  pb.U[0] = TMP0; pb.U[1] = TMP1;
  pb.Wb[0] = b0b; pb.Wb[1] = b1b; pb.Wb2 = b2b;
  pb.bias = beta2b; pb.XC = HH0; pb.N = N;
  fused_beta_kernel<<<GX, blk256, 0, stream>>>(pb);

  // ---- per-graph sums + 16-row GEMMs ----
  segsum_kernel<<<GX, blk256, 0, stream>>>(HH0, batch, states, gsel, gsum, N);
  small16_kernel<<<G, blk256, 0, stream>>>(gsel, gsum, g1W, g2W, A16b, B16b);

  // ---- gamma stage ----
  g3_kernel<<<GX, blk256, 0, stream>>>(HH0, A16b, B16b, batch, g0b, g3b, g4W, g4b, out, N);
}

// Round 16
// 405.850 us; speedup vs baseline: 1.1880x; 1.1880x over previous
//
#include <hip/hip_runtime.h>

typedef short s8v __attribute__((ext_vector_type(8)));
typedef float f32x4 __attribute__((ext_vector_type(4)));

#define LRELU(v) ((v) > 0.f ? (v) : 0.2f * (v))

constexpr int NBK = 391;   // (50000+127)/128 node buckets
constexpr int TILE = 2048; // edges per bin-pass block (391 blocks)
constexpr int CAP = 4096;  // fixed slab capacity per bucket

__device__ __forceinline__ float b2f(unsigned short b) {
  return __uint_as_float(((unsigned int)b) << 16);
}
__device__ __forceinline__ unsigned short f2b(float f) {
  unsigned int x = __float_as_uint(f);
  x += 0x7fffu + ((x >> 16) & 1u);
  return (unsigned short)(x >> 16);
}
__device__ __forceinline__ unsigned int pack2(float lo, float hi) {
  return ((unsigned int)f2b(hi) << 16) | (unsigned int)f2b(lo);
}

// ---------------- fused two-layer MLP: h = lin(lrelu(a1(x)))  ----------------
struct FArgs {
  const unsigned short* X[2];
  const unsigned short* W1[2];
  const float* b1[2];
  const float* a0p[2];
  const float* rowsum[2];
  const unsigned short* W2[2];
  const float* b2[2];
  unsigned short* H[2];
  const float* states;
  int N;
};

__global__ __launch_bounds__(256) void fused_mlp_kernel(FArgs fa)
{
  __shared__ __align__(16) unsigned short Ws[128 * 128];  // W1 then W2 (32KB)
  __shared__ __align__(16) unsigned short Tp[128 * 128];  // swizzled tmp tile (32KB)
  const int d = blockIdx.y;
  const int tid = threadIdx.x;
  const int lane = tid & 63;
  const int w = tid >> 6;
  const int l15 = lane & 15;
  const int g = lane >> 4;
  const int m0 = blockIdx.x * 128;
  const int N = fa.N;

#pragma unroll
  for (int j = 0; j < 8; ++j) {
    int idx = tid + j * 256;
    int o = idx >> 4, c = idx & 15;
    uint4 v = *(const uint4*)(fa.W1[d] + (size_t)o * 128 + c * 8);
    *(uint4*)&Ws[o * 128 + (c ^ (o & 15)) * 8] = v;
  }
  s8v a[2][4];
#pragma unroll
  for (int mf = 0; mf < 2; ++mf) {
    int row = m0 + w * 32 + mf * 16 + l15;
    const unsigned short* ar = fa.X[d] + (size_t)row * 128 + g * 8;
#pragma unroll
    for (int ks = 0; ks < 4; ++ks) {
      s8v t = {};
      if (row < N) t = *(const s8v*)(ar + ks * 32);
      a[mf][ks] = t;
    }
  }
  f32x4 zero4 = {0.f, 0.f, 0.f, 0.f};
  f32x4 acc[2][8];
#pragma unroll
  for (int mf = 0; mf < 2; ++mf)
#pragma unroll
    for (int nf = 0; nf < 8; ++nf) acc[mf][nf] = zero4;
  __syncthreads();
#pragma unroll
  for (int ks = 0; ks < 4; ++ks) {
#pragma unroll
    for (int nf = 0; nf < 8; ++nf) {
      int c = ks * 4 + g;
      s8v b = *(const s8v*)&Ws[(nf * 16 + l15) * 128 + (c ^ l15) * 8];
      acc[0][nf] = __builtin_amdgcn_mfma_f32_16x16x32_bf16(a[0][ks], b, acc[0][nf], 0, 0, 0);
      acc[1][nf] = __builtin_amdgcn_mfma_f32_16x16x32_bf16(a[1][ks], b, acc[1][nf], 0, 0, 0);
    }
  }
  const float a0 = fa.a0p[d][0];
#pragma unroll
  for (int mf = 0; mf < 2; ++mf) {
#pragma unroll
    for (int r = 0; r < 4; ++r) {
      int lrow = w * 32 + mf * 16 + g * 4 + r;
      int row = m0 + lrow;
      float sa = (row < N) ? fa.states[row] * a0 : 0.f;
#pragma unroll
      for (int nf = 0; nf < 8; ++nf) {
        int col = nf * 16 + l15;
        float v = 0.f;
        if (row < N) {
          v = acc[mf][nf][r] + fa.b1[d][col] + sa * fa.rowsum[d][col];
          v = LRELU(v);
        }
        int cch = col >> 3;
        Tp[lrow * 128 + ((cch ^ (lrow & 15)) << 3) + (col & 7)] = f2b(v);
      }
    }
  }
  __syncthreads();
#pragma unroll
  for (int j = 0; j < 8; ++j) {
    int idx = tid + j * 256;
    int o = idx >> 4, c = idx & 15;
    uint4 v = *(const uint4*)(fa.W2[d] + (size_t)o * 128 + c * 8);
    *(uint4*)&Ws[o * 128 + (c ^ (o & 15)) * 8] = v;
  }
  __syncthreads();
#pragma unroll
  for (int mf = 0; mf < 2; ++mf) {
    int lrow = w * 32 + mf * 16 + l15;
#pragma unroll
    for (int ks = 0; ks < 4; ++ks) {
      int c2 = ks * 4 + g;
      a[mf][ks] = *(const s8v*)&Tp[lrow * 128 + ((c2 ^ (lrow & 15)) << 3)];
    }
  }
#pragma unroll
  for (int mf = 0; mf < 2; ++mf)
#pragma unroll
    for (int nf = 0; nf < 8; ++nf) acc[mf][nf] = zero4;
#pragma unroll
  for (int ks = 0; ks < 4; ++ks) {
#pragma unroll
    for (int nf = 0; nf < 8; ++nf) {
      int c = ks * 4 + g;
      s8v b = *(const s8v*)&Ws[(nf * 16 + l15) * 128 + (c ^ l15) * 8];
      acc[0][nf] = __builtin_amdgcn_mfma_f32_16x16x32_bf16(a[0][ks], b, acc[0][nf], 0, 0, 0);
      acc[1][nf] = __builtin_amdgcn_mfma_f32_16x16x32_bf16(a[1][ks], b, acc[1][nf], 0, 0, 0);
    }
  }
#pragma unroll
  for (int mf = 0; mf < 2; ++mf) {
#pragma unroll
    for (int r = 0; r < 4; ++r) {
      int row = m0 + w * 32 + mf * 16 + g * 4 + r;
      if (row >= N) continue;
      unsigned short* crow = fa.H[d] + (size_t)row * 128;
#pragma unroll
      for (int nf = 0; nf < 8; ++nf) {
        int col = nf * 16 + l15;
        crow[col] = f2b(acc[mf][nf][r] + fa.b2[d][col]);
      }
    }
  }
}

// ---------------- fused beta (64KB LDS) ----------------
struct PBArgs {
  const unsigned short* U[2];
  const unsigned short* Wb[2];
  const unsigned short* Wb2;
  const float* bias;
  unsigned short* XC;
  int N;
};

__global__ __launch_bounds__(256) void fused_beta_kernel(PBArgs pa)
{
  __shared__ __align__(16) unsigned short Ws[128 * 128];
  __shared__ __align__(16) unsigned short Tp[128 * 128];
  const int tid = threadIdx.x;
  const int lane = tid & 63;
  const int w = tid >> 6;
  const int l15 = lane & 15;
  const int g = lane >> 4;
  const int m0 = blockIdx.x * 128;
  const int N = pa.N;
  f32x4 zero4 = {0.f, 0.f, 0.f, 0.f};
  s8v a[2][4];
  f32x4 accf[2][8];
#pragma unroll
  for (int mf = 0; mf < 2; ++mf)
#pragma unroll
    for (int nf = 0; nf < 8; ++nf) accf[mf][nf] = zero4;

  for (int ph = 0; ph < 2; ++ph) {
#pragma unroll
    for (int j = 0; j < 8; ++j) {
      int idx = tid + j * 256;
      int o = idx >> 4, c = idx & 15;
      uint4 v = *(const uint4*)(pa.Wb[ph] + (size_t)o * 128 + c * 8);
      *(uint4*)&Ws[o * 128 + (c ^ (o & 15)) * 8] = v;
    }
#pragma unroll
    for (int mf = 0; mf < 2; ++mf) {
      int row = m0 + w * 32 + mf * 16 + l15;
      const unsigned short* ar = pa.U[ph] + (size_t)row * 128 + g * 8;
#pragma unroll
      for (int ks = 0; ks < 4; ++ks) {
        s8v t = {};
        if (row < N) t = *(const s8v*)(ar + ks * 32);
        a[mf][ks] = t;
      }
    }
    f32x4 acc[2][8];
#pragma unroll
    for (int mf = 0; mf < 2; ++mf)
#pragma unroll
      for (int nf = 0; nf < 8; ++nf) acc[mf][nf] = zero4;
    __syncthreads();
#pragma unroll
    for (int ks = 0; ks < 4; ++ks) {
#pragma unroll
      for (int nf = 0; nf < 8; ++nf) {
        int c = ks * 4 + g;
        s8v b = *(const s8v*)&Ws[(nf * 16 + l15) * 128 + (c ^ l15) * 8];
        acc[0][nf] = __builtin_amdgcn_mfma_f32_16x16x32_bf16(a[0][ks], b, acc[0][nf], 0, 0, 0);
        acc[1][nf] = __builtin_amdgcn_mfma_f32_16x16x32_bf16(a[1][ks], b, acc[1][nf], 0, 0, 0);
      }
    }
    __syncthreads();
#pragma unroll
    for (int mf = 0; mf < 2; ++mf) {
#pragma unroll
      for (int r = 0; r < 4; ++r) {
        int lrow = w * 32 + mf * 16 + g * 4 + r;
        int row = m0 + lrow;
#pragma unroll
        for (int nf = 0; nf < 8; ++nf) {
          int col = nf * 16 + l15;
          float v = (row < N) ? acc[mf][nf][r] : 0.f;
          int cch = col >> 3;
          Tp[lrow * 128 + ((cch ^ (lrow & 15)) << 3) + (col & 7)] = f2b(v);
        }
      }
    }
    __syncthreads();
#pragma unroll
    for (int j = 0; j < 8; ++j) {
      int idx = tid + j * 256;
      int o = idx >> 4, c = idx & 15;
      uint4 v = *(const uint4*)(pa.Wb2 + (size_t)o * 256 + ph * 128 + c * 8);
      *(uint4*)&Ws[o * 128 + (c ^ (o & 15)) * 8] = v;
    }
#pragma unroll
    for (int mf = 0; mf < 2; ++mf) {
      int lrow = w * 32 + mf * 16 + l15;
#pragma unroll
      for (int ks = 0; ks < 4; ++ks) {
        int c2 = ks * 4 + g;
        a[mf][ks] = *(const s8v*)&Tp[lrow * 128 + ((c2 ^ (lrow & 15)) << 3)];
      }
    }
    __syncthreads();
#pragma unroll
    for (int ks = 0; ks < 4; ++ks) {
#pragma unroll
      for (int nf = 0; nf < 8; ++nf) {
        int c = ks * 4 + g;
        s8v b = *(const s8v*)&Ws[(nf * 16 + l15) * 128 + (c ^ l15) * 8];
        accf[0][nf] = __builtin_amdgcn_mfma_f32_16x16x32_bf16(a[0][ks], b, accf[0][nf], 0, 0, 0);
        accf[1][nf] = __builtin_amdgcn_mfma_f32_16x16x32_bf16(a[1][ks], b, accf[1][nf], 0, 0, 0);
      }
    }
    __syncthreads();
  }
#pragma unroll
  for (int mf = 0; mf < 2; ++mf) {
#pragma unroll
    for (int r = 0; r < 4; ++r) {
      int row = m0 + w * 32 + mf * 16 + g * 4 + r;
      if (row >= N) continue;
      unsigned short* crow = pa.XC + (size_t)row * 128;
#pragma unroll
      for (int nf = 0; nf < 8; ++nf) {
        int col = nf * 16 + l15;
        float v = accf[mf][nf][r] + pa.bias[col];
        crow[col] = f2b(LRELU(v));
      }
    }
  }
}

// ---------------- g3 GEMM with fused g0 stage + final dot ----------------
__global__ __launch_bounds__(256) void g3_kernel(
    const unsigned short* __restrict__ xc,
    const unsigned short* __restrict__ A16,
    const unsigned short* __restrict__ B16,
    const int* __restrict__ batch,
    const unsigned short* __restrict__ W0,
    const unsigned short* __restrict__ W3,
    const float* __restrict__ g4W,
    const float* __restrict__ g4b,
    float* __restrict__ out, int N)
{
  constexpr int NF = 12;
  __shared__ __align__(16) unsigned short Ws[192 * 128];
  __shared__ __align__(16) unsigned short Tp[128 * 128];
  const int tid = threadIdx.x;
  const int lane = tid & 63;
  const int w = tid >> 6;
  const int l15 = lane & 15;
  const int g = lane >> 4;
  const int m0 = blockIdx.x * 128;

  f32x4 zero4 = {0.f, 0.f, 0.f, 0.f};
  s8v a[2][4];

#pragma unroll
  for (int j = 0; j < 8; ++j) {
    int idx = tid + j * 256;
    int o = idx >> 4, c = idx & 15;
    uint4 v = *(const uint4*)(W0 + (size_t)o * 128 + c * 8);
    *(uint4*)&Ws[o * 128 + (c ^ (o & 15)) * 8] = v;
  }
#pragma unroll
  for (int mf = 0; mf < 2; ++mf) {
    int row = m0 + w * 32 + mf * 16 + l15;
    const unsigned short* ar = xc + (size_t)row * 128 + g * 8;
#pragma unroll
    for (int ks = 0; ks < 4; ++ks) {
      s8v t = {};
      if (row < N) t = *(const s8v*)(ar + ks * 32);
      a[mf][ks] = t;
    }
  }
  {
    f32x4 acc1[2][8];
#pragma unroll
    for (int mf = 0; mf < 2; ++mf)
#pragma unroll
      for (int nf = 0; nf < 8; ++nf) acc1[mf][nf] = zero4;
    __syncthreads();
#pragma unroll
    for (int ks = 0; ks < 4; ++ks) {
#pragma unroll
      for (int nf = 0; nf < 8; ++nf) {
        int c = ks * 4 + g;
        s8v b = *(const s8v*)&Ws[(nf * 16 + l15) * 128 + (c ^ l15) * 8];
        acc1[0][nf] = __builtin_amdgcn_mfma_f32_16x16x32_bf16(a[0][ks], b, acc1[0][nf], 0, 0, 0);
        acc1[1][nf] = __builtin_amdgcn_mfma_f32_16x16x32_bf16(a[1][ks], b, acc1[1][nf], 0, 0, 0);
      }
    }
#pragma unroll
    for (int mf = 0; mf < 2; ++mf) {
#pragma unroll
      for (int r = 0; r < 4; ++r) {
        int lrow = w * 32 + mf * 16 + g * 4 + r;
        int row = m0 + lrow;
#pragma unroll
        for (int nf = 0; nf < 8; ++nf) {
          int col = nf * 16 + l15;
          float v = (row < N) ? acc1[mf][nf][r] : 0.f;
          int cch = col >> 3;
          Tp[lrow * 128 + ((cch ^ (lrow & 15)) << 3) + (col & 7)] = f2b(v);
        }
      }
    }
  }
  __syncthreads();

  f32x4 acc[2][NF];
#pragma unroll
  for (int mf = 0; mf < 2; ++mf)
#pragma unroll
    for (int nf = 0; nf < NF; ++nf) acc[mf][nf] = zero4;

  int brow[2];
#pragma unroll
  for (int mf = 0; mf < 2; ++mf) {
    int row = m0 + w * 32 + mf * 16 + l15;
    brow[mf] = (row < N) ? batch[row] : 0;
  }

  for (int kk = 0; kk < 384; kk += 128) {
#pragma unroll
    for (int j = 0; j < NF; ++j) {
      int idx = tid + j * 256;
      int o = idx >> 4, c = idx & 15;
      uint4 v = *(const uint4*)(W3 + (size_t)o * 384 + kk + c * 8);
      *(uint4*)&Ws[o * 128 + (c ^ (o & 15)) * 8] = v;
    }
    if (kk == 0) {
#pragma unroll
      for (int mf = 0; mf < 2; ++mf) {
        int lrow = w * 32 + mf * 16 + l15;
#pragma unroll
        for (int ks = 0; ks < 4; ++ks) {
          int c2 = ks * 4 + g;
          a[mf][ks] = *(const s8v*)&Tp[lrow * 128 + ((c2 ^ (lrow & 15)) << 3)];
        }
      }
    } else {
#pragma unroll
      for (int mf = 0; mf < 2; ++mf) {
        int row = m0 + w * 32 + mf * 16 + l15;
        const unsigned short* ar = ((kk == 128) ? A16 : B16) + (size_t)brow[mf] * 128 + g * 8;
#pragma unroll
        for (int ks = 0; ks < 4; ++ks) {
          s8v t = {};
          if (row < N) t = *(const s8v*)(ar + ks * 32);
          a[mf][ks] = t;
        }
      }
    }
    __syncthreads();
#pragma unroll
    for (int ks = 0; ks < 4; ++ks) {
#pragma unroll
      for (int nf = 0; nf < NF; ++nf) {
        int c = ks * 4 + g;
        s8v b = *(const s8v*)&Ws[(nf * 16 + l15) * 128 + (c ^ l15) * 8];
        acc[0][nf] = __builtin_amdgcn_mfma_f32_16x16x32_bf16(a[0][ks], b, acc[0][nf], 0, 0, 0);
        acc[1][nf] = __builtin_amdgcn_mfma_f32_16x16x32_bf16(a[1][ks], b, acc[1][nf], 0, 0, 0);
      }
    }
    if (kk < 256) __syncthreads();
  }

  float w4[NF];
#pragma unroll
  for (int nf = 0; nf < NF; ++nf) w4[nf] = g4W[nf * 16 + l15];
  const float gb = g4b[0];

#pragma unroll
  for (int mf = 0; mf < 2; ++mf) {
#pragma unroll
    for (int r = 0; r < 4; ++r) {
      int row = m0 + w * 32 + mf * 16 + g * 4 + r;
      float dot = 0.f;
#pragma unroll
      for (int nf = 0; nf < NF; ++nf) {
        float v = acc[mf][nf][r];
        v = LRELU(v);
        dot += v * w4[nf];
      }
#pragma unroll
      for (int m = 1; m < 16; m <<= 1) dot += __shfl_xor(dot, m, 16);
      if (l15 == 0 && row < N) out[row] = dot + gb;
    }
  }
}

// ---------------- preamble: convert weights + rowsums + init x split + zero bcur ----------------
struct PreArgs {
  const float* src[9];
  unsigned short* wreg;
  int cum[10];
  const float* a1; const float* a2; float* rs;
  const float* x;
  unsigned short* x1; unsigned short* x2;
  int* bcur0; int* bcur1;
  int n;
};

__global__ __launch_bounds__(256) void preamble_kernel(PreArgs pa)
{
  const int NINIT = 3125;
  const int NCONV = 172;
  int b = blockIdx.x;
  int t = threadIdx.x;
  if (b < NINIT) {
    int idx = b * 256 + t;
    if (idx < pa.n * 16) {
      int r = idx >> 4, c = idx & 15;
      const float* xr = pa.x + (size_t)r * 256 + c * 8;
      float4 p0 = *(const float4*)xr;
      float4 p1 = *(const float4*)(xr + 4);
      uint4 u1;
      u1.x = pack2(p0.x, p0.y); u1.y = pack2(p0.z, p0.w);
      u1.z = pack2(p1.x, p1.y); u1.w = pack2(p1.z, p1.w);
      float4 q0 = *(const float4*)(xr + 128);
      float4 q1 = *(const float4*)(xr + 132);
      uint4 u2;
      u2.x = pack2(q0.x, q0.y); u2.y = pack2(q0.z, q0.w);
      u2.z = pack2(q1.x, q1.y); u2.w = pack2(q1.z, q1.w);
      ((uint4*)(pa.x1 + (size_t)r * 128))[c] = u1;
      ((uint4*)(pa.x2 + (size_t)r * 128))[c] = u2;
    }
  } else if (b < NINIT + NCONV) {
    int e = ((b - NINIT) * 256 + t) * 8;
    if (e < pa.cum[9]) {
      int j = 0;
#pragma unroll
      for (int k = 1; k < 9; ++k) if (e >= pa.cum[k]) j = k;
      const float* s = pa.src[j] + (e - pa.cum[j]);
      float4 p0 = *(const float4*)s;
      float4 p1 = *(const float4*)(s + 4);
      uint4 u;
      u.x = pack2(p0.x, p0.y); u.y = pack2(p0.z, p0.w);
      u.z = pack2(p1.x, p1.y); u.w = pack2(p1.z, p1.w);
      *(uint4*)(pa.wreg + e) = u;
    }
  } else if (b < NINIT + NCONV + 6) {
    int j = b - NINIT - NCONV;
    if (t < 128) {
      const float* src = (j < 3) ? (pa.a1 + (size_t)j * 16384) : (pa.a2 + (size_t)(j - 3) * 16384);
      float s = 0.f;
      for (int k = 0; k < 128; ++k) s += src[t * 128 + k];
      pa.rs[j * 128 + t] = s;
    }
  } else {
    for (int i = t; i < NBK; i += 256) { pa.bcur0[i] = 0; pa.bcur1[i] = 0; }
  }
}

// ---------------- multi-split bin pass into fixed-cap per-bucket slabs ----------------
struct BinArgs {
  const int* s0; const int* s1; const float* ew;
  int* bcur0; int* bcur1;
  unsigned long long* bin0; unsigned long long* bin1;
  int E;
};
__global__ __launch_bounds__(256) void bin_kernel(BinArgs ba)
{
  __shared__ int hist0[NBK], hist1[NBK];
  __shared__ int base0[NBK], base1[NBK];
  const int t = threadIdx.x;
  const int e0 = blockIdx.x * TILE;
  const int e1 = min(e0 + TILE, ba.E);
  for (int i = t; i < NBK; i += 256) { hist0[i] = 0; hist1[i] = 0; }
  __syncthreads();
  for (int e = e0 + t; e < e1; e += 256) {
    atomicAdd(&hist0[ba.s0[e] >> 7], 1);
    atomicAdd(&hist1[ba.s1[e] >> 7], 1);
  }
  __syncthreads();
  for (int i = t; i < NBK; i += 256) {
    int c0 = hist0[i];
    base0[i] = c0 ? atomicAdd(&ba.bcur0[i], c0) : 0;
    int c1 = hist1[i];
    base1[i] = c1 ? atomicAdd(&ba.bcur1[i], c1) : 0;
  }
  __syncthreads();
  for (int i = t; i < NBK; i += 256) { hist0[i] = 0; hist1[i] = 0; }
  __syncthreads();
  for (int e = e0 + t; e < e1; e += 256) {
    int d0 = ba.s0[e], d1 = ba.s1[e];
    unsigned long long wb = (unsigned long long)__float_as_uint(ba.ew[e]) << 32;
    int b0 = d0 >> 7, b1 = d1 >> 7;
    int r0 = base0[b0] + atomicAdd(&hist0[b0], 1);
    if (r0 < CAP)
      ba.bin0[(size_t)b0 * CAP + r0] = wb | (unsigned int)((d0 & 127) << 16) | (unsigned int)d1;
    int r1 = base1[b1] + atomicAdd(&hist1[b1], 1);
    if (r1 < CAP)
      ba.bin1[(size_t)b1 * CAP + r1] = wb | (unsigned int)((d1 & 127) << 16) | (unsigned int)d0;
  }
}

// ---------------- bucket scan + gsel/gsum zero ----------------
struct BScanArgs { const int* cnt[2]; int* bbase[2]; float* gsel; float* gsum; };
__global__ __launch_bounds__(128) void bscan_kernel(BScanArgs a)
{
  __shared__ int ld[2][NBK];
  int wid = threadIdx.x >> 6, lane = threadIdx.x & 63;
  for (int i = threadIdx.x; i < 2048; i += 128) { a.gsel[i] = 0.f; a.gsum[i] = 0.f; }
  for (int i = lane; i < NBK; i += 64) ld[wid][i] = a.cnt[wid][i];
  __syncthreads();
  if (lane == 0) {
    int acc = 0;
    for (int i = 0; i < NBK; ++i) { int v = ld[wid][i]; ld[wid][i] = acc; acc += v; }
    a.bbase[wid][NBK] = acc;
  }
  __syncthreads();
  for (int i = lane; i < NBK; i += 64) a.bbase[wid][i] = ld[wid][i];
}

// ---------------- reorder: slab -> per-node CSR slots + row[] build ----------------
struct RArgs {
  const int* bbase[2];
  const unsigned long long* bin[2];
  unsigned int* comb[2];
  int* row[2];
  int n;
};
__global__ __launch_bounds__(256) void reorder_kernel(RArgs ra)
{
  const int d = blockIdx.y;
  const int b = blockIdx.x;
  const unsigned long long* __restrict__ bin = ra.bin[d] + (size_t)b * CAP;
  unsigned int* __restrict__ comb = ra.comb[d];
  int* __restrict__ row = ra.row[d];
  const int nb = b * 128;
  const int ne = min(nb + 128, ra.n);
  const int t = threadIdx.x;
  __shared__ int lcnt[128];
  __shared__ int lcur[128];
  __shared__ int wtot[4];
  if (t < 128) lcnt[t] = 0;
  const int span_beg = ra.bbase[d][b];
  const int span_end = ra.bbase[d][b + 1];
  const int cnt = span_end - span_beg;
  __syncthreads();
  for (int i = t; i < cnt; i += 256) {
    int nl = ((unsigned int)bin[i] >> 16) & 127;
    atomicAdd(&lcnt[nl], 1);
  }
  __syncthreads();
  int lane = t & 63, wv = t >> 6;
  int v = (t < 128) ? lcnt[t] : 0;
  int sc = v;
#pragma unroll
  for (int off = 1; off < 64; off <<= 1) {
    int u = __shfl_up(sc, off, 64);
    if (lane >= off) sc += u;
  }
  if (lane == 63) wtot[wv] = sc;
  __syncthreads();
  int excl = sc - v + ((wv == 1) ? wtot[0] : 0);
  if (t < 128) {
    lcur[t] = excl;
    if (nb + t < ne) row[nb + t] = span_beg + excl;
  }
  if (b == NBK - 1 && t == 0) row[ra.n] = span_end;
  __syncthreads();
  for (int i = t; i < cnt; i += 256) {
    unsigned long long r = bin[i];
    unsigned int lo = (unsigned int)r;
    float w = __uint_as_float((unsigned int)(r >> 32));
    int nl = (lo >> 16) & 127;
    int slot = atomicAdd(&lcur[nl], 1);
    comb[span_beg + slot] = (lo & 0xffffu) | ((unsigned int)f2b(w) << 16);
  }
}

// gather v4: one NODE per quarter-wave (16 lanes); uint4 (8 features) per lane; 8-edge chunks
struct GArgs {
  const int* rowstart[2];
  const unsigned int* comb[2];
  const unsigned short* h[2];
  unsigned short* xout[2];
  const unsigned int* add1[2];
  const unsigned int* add2[2];
  int n;
};
__global__ void gather_kernel(GArgs ga)
{
  int quad = blockIdx.x * (blockDim.x >> 6) + (threadIdx.x >> 6);
  int lane = threadIdx.x & 63;
  int sub = lane >> 4;        // node slot 0..3
  int fl = lane & 15;         // feature lane: uint4 = 8 bf16 features
  long long gnode = (long long)4 * quad + sub;
  bool valid = gnode < 2 * ga.n;
  int dir = (valid && gnode >= ga.n) ? 1 : 0;
  int node = valid ? (int)(gnode - (long long)dir * ga.n) : 0;
  const int* __restrict__ rowstart = ga.rowstart[dir];
  const unsigned int* __restrict__ comb = ga.comb[dir];
  const unsigned int* __restrict__ h = (const unsigned int*)ga.h[dir];
  int beg = rowstart[node], end = rowstart[node + 1];
  if (!valid) end = beg;
  int nch_own = (end - beg + 7) >> 3;
  int m1 = max(nch_own, __shfl_xor(nch_own, 16, 64));
  int nch = max(m1, __shfl_xor(m1, 32, 64));
  float a0 = 0.f, a1 = 0.f, a2 = 0.f, a3 = 0.f;
  float a4 = 0.f, a5 = 0.f, a6 = 0.f, a7 = 0.f;
  for (int ch = 0; ch < nch; ++ch) {
    int p0 = beg + ch * 8;
    unsigned int cc[8];
    uint4 uu[8];
#pragma unroll
    for (int i = 0; i < 8; ++i) {
      int pi = p0 + i;
      cc[i] = (pi < end) ? comb[pi] : 0u;
    }
#pragma unroll
    for (int i = 0; i < 8; ++i)
      uu[i] = *(const uint4*)(h + (size_t)(cc[i] & 0xffffu) * 64 + fl * 4);
#pragma unroll
    for (int i = 0; i < 8; ++i) {
      float wv = b2f((unsigned short)(cc[i] >> 16));
      a0 += wv * b2f((unsigned short)uu[i].x);
      a1 += wv * b2f((unsigned short)(uu[i].x >> 16));
      a2 += wv * b2f((unsigned short)uu[i].y);
      a3 += wv * b2f((unsigned short)(uu[i].y >> 16));
      a4 += wv * b2f((unsigned short)uu[i].z);
      a5 += wv * b2f((unsigned short)(uu[i].z >> 16));
      a6 += wv * b2f((unsigned short)uu[i].w);
      a7 += wv * b2f((unsigned short)(uu[i].w >> 16));
    }
  }
  float v0 = LRELU(a0), v1 = LRELU(a1), v2 = LRELU(a2), v3 = LRELU(a3);
  float v4 = LRELU(a4), v5 = LRELU(a5), v6 = LRELU(a6), v7 = LRELU(a7);
  if (ga.add1[0]) {
    uint4 ua = ((const uint4*)ga.add1[dir])[(size_t)node * 16 + fl];
    uint4 ub = ((const uint4*)ga.add2[dir])[(size_t)node * 16 + fl];
    v0 += b2f((unsigned short)ua.x) + b2f((unsigned short)ub.x);
    v1 += b2f((unsigned short)(ua.x >> 16)) + b2f((unsigned short)(ub.x >> 16));
    v2 += b2f((unsigned short)ua.y) + b2f((unsigned short)ub.y);
    v3 += b2f((unsigned short)(ua.y >> 16)) + b2f((unsigned short)(ub.y >> 16));
    v4 += b2f((unsigned short)ua.z) + b2f((unsigned short)ub.z);
    v5 += b2f((unsigned short)(ua.z >> 16)) + b2f((unsigned short)(ub.z >> 16));
    v6 += b2f((unsigned short)ua.w) + b2f((unsigned short)ub.w);
    v7 += b2f((unsigned short)(ua.w >> 16)) + b2f((unsigned short)(ub.w >> 16));
  }
  if (valid) {
    uint4 o;
    o.x = pack2(v0, v1);
    o.y = pack2(v2, v3);
    o.z = pack2(v4, v5);
    o.w = pack2(v6, v7);
    ((uint4*)(ga.xout[dir] + (size_t)node * 128))[fl] = o;
  }
}

// ---------------- parallel segment sum ----------------
__global__ __launch_bounds__(256) void segsum_kernel(
    const unsigned short* __restrict__ xc, const int* __restrict__ batch,
    const float* __restrict__ states,
    float* __restrict__ gsel, float* __restrict__ gsum, int n)
{
  int slot = threadIdx.x >> 6;
  int lane = threadIdx.x & 63;
  int r0 = blockIdx.x * 128 + slot * 32;
  if (r0 >= n) return;
  int r1 = min(r0 + 32, n);
  const unsigned int* __restrict__ xcu = (const unsigned int*)xc;
  float sel0 = 0.f, sel1 = 0.f, sum0 = 0.f, sum1 = 0.f;
  int cur = batch[r0];
  for (int r = r0; r < r1; r += 4) {
    unsigned int u[4]; int bb[4]; float st[4];
#pragma unroll
    for (int i = 0; i < 4; ++i) {
      int ri = min(r + i, r1 - 1);
      u[i] = xcu[(size_t)ri * 64 + lane];
      bb[i] = batch[ri];
      st[i] = states[ri];
    }
    int m = min(4, r1 - r);
#pragma unroll
    for (int i = 0; i < 4; ++i) {
      if (i >= m) break;
      if (bb[i] != cur) {
        atomicAdd(&gsel[cur * 128 + lane * 2], sel0);
        atomicAdd(&gsel[cur * 128 + lane * 2 + 1], sel1);
        atomicAdd(&gsum[cur * 128 + lane * 2], sum0);
        atomicAdd(&gsum[cur * 128 + lane * 2 + 1], sum1);
        sel0 = sel1 = sum0 = sum1 = 0.f;
        cur = bb[i];
      }
      float lo = b2f((unsigned short)u[i]);
      float hi = b2f((unsigned short)(u[i] >> 16));
      sum0 += lo; sum1 += hi;
      if (st[i] == 1.0f) { sel0 += lo; sel1 += hi; }
    }
  }
  atomicAdd(&gsel[cur * 128 + lane * 2], sel0);
  atomicAdd(&gsel[cur * 128 + lane * 2 + 1], sel1);
  atomicAdd(&gsum[cur * 128 + lane * 2], sum0);
  atomicAdd(&gsum[cur * 128 + lane * 2 + 1], sum1);
}

__global__ void small16_kernel(const float* __restrict__ gsel, const float* __restrict__ gsum,
                               const float* __restrict__ g1W, const float* __restrict__ g2W,
                               unsigned short* __restrict__ A16, unsigned short* __restrict__ B16)
{
  int r = blockIdx.x, t = threadIdx.x, o = t & 127;
  const float* src = (t < 128) ? gsel : gsum;
  const float* Wm  = (t < 128) ? g1W : g2W;
  float acc = 0.f;
  for (int k = 0; k < 128; ++k) acc += src[r * 128 + k] * Wm[o * 128 + k];
  unsigned short* dst = (t < 128) ? A16 : B16;
  dst[r * 128 + o] = f2b(acc);
}

extern "C" void kernel_launch(void* const* d_in, const int* in_sizes, int n_in,
                              void* d_out, int out_size, void* d_ws, size_t ws_size,
                              hipStream_t stream)
{
  const int N = 50000, F = 128, E = 800000, G = 16, T = 3;
  const float* x      = (const float*)d_in[0];
  const int*   ei     = (const int*)d_in[1];
  const int*   s0     = ei;
  const int*   s1     = ei + E;
  const float* ew     = (const float*)d_in[2];
  const int*   batch  = (const int*)d_in[3];
  const float* states = (const float*)d_in[4];
  const float* p_a0[2]   = {(const float*)d_in[5],  (const float*)d_in[10]};
  const float* p_a1W[2]  = {(const float*)d_in[6],  (const float*)d_in[11]};
  const float* p_a1b[2]  = {(const float*)d_in[7],  (const float*)d_in[12]};
  const float* p_linW[2] = {(const float*)d_in[8],  (const float*)d_in[13]};
  const float* p_linb[2] = {(const float*)d_in[9],  (const float*)d_in[14]};
  const float* beta0W = (const float*)d_in[15];
  const float* beta1W = (const float*)d_in[16];
  const float* beta2W = (const float*)d_in[17];
  const float* beta2b = (const float*)d_in[18];
  const float* g0W = (const float*)d_in[19];
  const float* g1W = (const float*)d_in[20];
  const float* g2W = (const float*)d_in[21];
  const float* g3W = (const float*)d_in[22];
  const float* g4W = (const float*)d_in[23];
  const float* g4b = (const float*)d_in[24];
  float* out = (float*)d_out;

  char* p = (char*)d_ws;
  auto alloc = [&](size_t bytes) {
    char* r = p;
    p += (bytes + 255) & ~(size_t)255;
    return r;
  };
  const size_t NFb2 = (size_t)N * F * sizeof(unsigned short);  // 12.8 MB
  unsigned short* X1[3] = {(unsigned short*)alloc(NFb2), (unsigned short*)alloc(NFb2),
                           (unsigned short*)alloc(NFb2)};
  unsigned short* X2[3] = {(unsigned short*)alloc(NFb2), (unsigned short*)alloc(NFb2),
                           (unsigned short*)alloc(NFb2)};
  unsigned short* TMP0 = (unsigned short*)alloc(NFb2);
  unsigned short* TMP1 = (unsigned short*)alloc(NFb2);
  unsigned short* HH0  = (unsigned short*)alloc(NFb2);
  unsigned short* HH1  = (unsigned short*)alloc(NFb2);
  int*   row0 = (int*)alloc((size_t)(N + 1) * 4);
  int*   row1 = (int*)alloc((size_t)(N + 1) * 4);
  int*   bbase0 = (int*)alloc((size_t)(NBK + 1) * 4);
  int*   bbase1 = (int*)alloc((size_t)(NBK + 1) * 4);
  int*   bcur0 = (int*)alloc((size_t)NBK * 4);
  int*   bcur1 = (int*)alloc((size_t)NBK * 4);
  unsigned long long* bin0 = (unsigned long long*)alloc((size_t)NBK * CAP * 8);
  unsigned long long* bin1 = (unsigned long long*)alloc((size_t)NBK * CAP * 8);
  unsigned int* comb0 = (unsigned int*)alloc((size_t)E * 4);
  unsigned int* comb1 = (unsigned int*)alloc((size_t)E * 4);
  float* gsel = (float*)alloc((size_t)G * F * 4);
  float* gsum = (float*)alloc((size_t)G * F * 4);
  unsigned short* A16b = (unsigned short*)alloc((size_t)G * F * 2);
  unsigned short* B16b = (unsigned short*)alloc((size_t)G * F * 2);
  unsigned short* wreg = (unsigned short*)alloc((size_t)352256 * 2);
  float* rs = (float*)alloc((size_t)6 * 128 * 4);

  unsigned short* a1Wb[2]  = {wreg + 0,      wreg + 49152};
  unsigned short* linWb[2] = {wreg + 98304,  wreg + 147456};
  unsigned short* b0b = wreg + 196608;
  unsigned short* b1b = wreg + 212992;
  unsigned short* b2b = wreg + 229376;
  unsigned short* g0b = wreg + 262144;
  unsigned short* g3b = wreg + 278528;

  const dim3 blk256(256);
  const int GX = (N + 127) / 128;
  const int EB = (E + TILE - 1) / TILE;

  // ---- preamble: convert + rowsum + init + zero-bcur in ONE launch ----
  PreArgs pra;
  pra.src[0] = p_a1W[0];  pra.src[1] = p_a1W[1];
  pra.src[2] = p_linW[0]; pra.src[3] = p_linW[1];
  pra.src[4] = beta0W;    pra.src[5] = beta1W;  pra.src[6] = beta2W;
  pra.src[7] = g0W;       pra.src[8] = g3W;
  pra.wreg = wreg;
  int cums[10] = {0, 49152, 98304, 147456, 196608, 212992, 229376, 262144, 278528, 352256};
  for (int i = 0; i < 10; ++i) pra.cum[i] = cums[i];
  pra.a1 = p_a1W[0]; pra.a2 = p_a1W[1]; pra.rs = rs;
  pra.x = x; pra.x1 = X1[0]; pra.x2 = X2[0];
  pra.bcur0 = bcur0; pra.bcur1 = bcur1;
  pra.n = N;
  preamble_kernel<<<3125 + 172 + 6 + 1, blk256, 0, stream>>>(pra);

  // ---- CSR build ----
  BinArgs bna;
  bna.s0 = s0; bna.s1 = s1; bna.ew = ew;
  bna.bcur0 = bcur0; bna.bcur1 = bcur1;
  bna.bin0 = bin0; bna.bin1 = bin1;
  bna.E = E;
  bin_kernel<<<EB, blk256, 0, stream>>>(bna);
  BScanArgs bsa;
  bsa.cnt[0] = bcur0; bsa.cnt[1] = bcur1;
  bsa.bbase[0] = bbase0; bsa.bbase[1] = bbase1;
  bsa.gsel = gsel; bsa.gsum = gsum;
  bscan_kernel<<<1, 128, 0, stream>>>(bsa);
  RArgs ra;
  ra.bbase[0] = bbase0; ra.bbase[1] = bbase1;
  ra.bin[0] = bin0; ra.bin[1] = bin1;
  ra.comb[0] = comb0; ra.comb[1] = comb1;
  ra.row[0] = row0; ra.row[1] = row1;
  ra.n = N;
  reorder_kernel<<<dim3(NBK, 2), blk256, 0, stream>>>(ra);

  // ---- T-loop ----
  for (int t = 0; t < T; ++t) {
    int rv = t % 3, wv = (t + 1) % 3;

    FArgs fa;
    fa.X[0] = X1[rv];  fa.X[1] = X2[rv];
    fa.W1[0] = a1Wb[0] + t * 16384;  fa.W1[1] = a1Wb[1] + t * 16384;
    fa.b1[0] = p_a1b[0] + t * F;     fa.b1[1] = p_a1b[1] + t * F;
    fa.a0p[0] = p_a0[0] + t;         fa.a0p[1] = p_a0[1] + t;
    fa.rowsum[0] = rs + t * 128;     fa.rowsum[1] = rs + (3 + t) * 128;
    fa.W2[0] = linWb[0] + t * 16384; fa.W2[1] = linWb[1] + t * 16384;
    fa.b2[0] = p_linb[0] + t * F;    fa.b2[1] = p_linb[1] + t * F;
    fa.H[0] = HH0;  fa.H[1] = HH1;
    fa.states = states;  fa.N = N;
    fused_mlp_kernel<<<dim3(GX, 2), blk256, 0, stream>>>(fa);

    GArgs ga;
    ga.rowstart[0] = row0; ga.rowstart[1] = row1;
    ga.comb[0] = comb0;    ga.comb[1] = comb1;
    ga.h[0] = HH0;         ga.h[1] = HH1;
    if (t == T - 1) {
      ga.xout[0] = TMP0;  ga.xout[1] = TMP1;
      ga.add1[0] = (const unsigned int*)X1[1];  ga.add1[1] = (const unsigned int*)X2[1];
      ga.add2[0] = (const unsigned int*)X1[2];  ga.add2[1] = (const unsigned int*)X2[2];
    } else {
      ga.xout[0] = X1[wv];  ga.xout[1] = X2[wv];
      ga.add1[0] = nullptr; ga.add1[1] = nullptr;
      ga.add2[0] = nullptr; ga.add2[1] = nullptr;
    }
    ga.n = N;
    gather_kernel<<<(2 * N + 15) / 16, blk256, 0, stream>>>(ga);
  }

  // ---- fused beta ----
  PBArgs pb;
  pb.U[0] = TMP0; pb.U[1] = TMP1;
  pb.Wb[0] = b0b; pb.Wb[1] = b1b; pb.Wb2 = b2b;
  pb.bias = beta2b; pb.XC = HH0; pb.N = N;
  fused_beta_kernel<<<GX, blk256, 0, stream>>>(pb);

  // ---- per-graph sums + 16-row GEMMs ----
  segsum_kernel<<<GX, blk256, 0, stream>>>(HH0, batch, states, gsel, gsum, N);
  small16_kernel<<<G, blk256, 0, stream>>>(gsel, gsum, g1W, g2W, A16b, B16b);

  // ---- gamma stage ----
  g3_kernel<<<GX, blk256, 0, stream>>>(HH0, A16b, B16b, batch, g0b, g3b, g4W, g4b, out, N);
}